// Round 19
// baseline (621.669 us; speedup 1.0000x reference)
//
#include <hip/hip_runtime.h>
#include <hip/hip_bf16.h>
#include <math.h>

#define DD     128
#define NWAVE  16
#define TPB    (NWAVE*64)    // 1024 threads
#define TROWS  (NWAVE*16)    // 256 rows per tile (16 rows per wave)
#define GRID_MLP 256
#define MAXG   16384

typedef __attribute__((ext_vector_type(8)))  short bf16x8;
typedef __attribute__((ext_vector_type(4)))  float f32x4;

// static device scratch (rewritten every launch -> deterministic)
// 16x16x32 frag layout: [LT][ks4][ft8][lane][8], LT = L*2+T
// A/B frag: lane l holds M[i = ft*16 + (l&15)][k = ks*32 + (l>>4)*8 + r], r=0..7
// W1 (L=0) rows are PERMUTED by pi(ft,h,j) = 32*(ft>>1) + 8h + 4*(ft&1) + j
__device__ __align__(16) unsigned short g_wfrag[4*4*8*64*8]; // 128 KB
__device__ __align__(16) float g_b1p[DD];
__device__ float g_m, g_invZ;
__device__ float g_pm[MAXG], g_ps[MAXG];

__device__ __forceinline__ unsigned short f2b(float x){
    union { __hip_bfloat16 b; unsigned short u; } c;
    c.b = __float2bfloat16(x);
    return c.u;
}

// truncation-hi split: hi = upper 16 bits of f32, lo = RNE-bf16(x - hi).
__device__ __forceinline__ void split2(float x, unsigned short& h, unsigned short& l){
    unsigned int bx = __float_as_uint(x);
    float hf = __uint_as_float(bx & 0xFFFF0000u);
    h = (unsigned short)(bx >> 16);
    l = f2b(x - hf);
}

// ---- prep: blocks 0..31 build frags (W1 feature-permuted); block 32 builds b1p ----
__global__ __launch_bounds__(256)
void k_prep(const float* __restrict__ W1, const float* __restrict__ W2,
            const float* __restrict__ b1, const float* __restrict__ u)
{
    __shared__ float red[256];
    __shared__ float us[128];
    const int tid = threadIdx.x;

    if (blockIdx.x < 32){
        const int t    = blockIdx.x*256 + tid;           // 0..8191
        const int lane = t & 63;
        const int ft   = (t>>6) & 7;                     // 8 tiles of 16
        const int ks   = (t>>9) & 3;                     // 4 k-steps of 32
        const int T    = (t>>11) & 1;                    // 0 = hi, 1 = lo
        const int L    = (t>>12) & 1;                    // 0 = W1, 1 = W2
        const int l15  = lane & 15;
        int col;
        if (L == 0){
            // permuted W1 row: pi(ft, h=(l15>>2), j=(l15&3))
            col = 32*(ft>>1) + 8*(l15>>2) + 4*(ft&1) + (l15&3);
        } else {
            col = ft*16 + l15;
        }
        const int kb   = ks*32 + ((lane>>4) << 3);
        const float* src = L ? (W2 + (size_t)col*128 + kb) : (W1 + (size_t)col*256 + kb);
        unsigned short o[8];
        #pragma unroll
        for (int r = 0; r < 8; ++r){
            float x = src[r];
            unsigned short h, l;
            split2(x, h, l);
            o[r] = T ? l : h;
        }
        ushort4* dst = (ushort4*)&g_wfrag[(size_t)t * 8];
        dst[0] = *(ushort4*)&o[0];
        dst[1] = *(ushort4*)&o[4];
    } else {
        if (tid < 128) us[tid] = u[tid];
        __syncthreads();
        const int c = tid & 127, part = tid >> 7;
        const float* wr = W1 + (size_t)c*256 + 128 + part*64;
        float a = 0.f;
        #pragma unroll
        for (int j = 0; j < 64; ++j) a = fmaf(wr[j], us[part*64 + j], a);
        red[tid] = a;
        __syncthreads();
        if (part == 0) g_b1p[c] = red[c] + red[128 + c] + b1[c];
    }
}

__global__ __launch_bounds__(TPB, 4)
void k_mlp(const float* __restrict__ node1,
           const float* __restrict__ b2,
           const float* __restrict__ W3,
           float* __restrict__ out, int n)
{
    extern __shared__ __align__(16) unsigned short Wlds[];   // 131072 B
    const int tid  = threadIdx.x;
    const int lane = tid & 63;
    const int wv   = __builtin_amdgcn_readfirstlane(tid >> 6);
    const int hg4  = lane >> 4;
    const int r16  = lane & 15;

    // ---- stage ALL W-frags into LDS once ----
    {
        const f32x4* gs = (const f32x4*)g_wfrag;
        f32x4* ls = (f32x4*)Wlds;
        #pragma unroll
        for (int i = 0; i < 8; ++i) ls[i*TPB + tid] = gs[i*TPB + tid];
    }
    __syncthreads();   // the ONLY barrier

    const bf16x8* WL = (const bf16x8*)Wlds;   // [((LT*4+ks)*8+ft)*64 + lane]
    const int ntiles = (n + TROWS - 1) / TROWS;

    // t-invariant per-lane weights for L2 bias / layer3
    float b2v[8], w3v[8];
    #pragma unroll
    for (int oft = 0; oft < 8; ++oft){
        b2v[oft] = b2[oft*16 + r16];
        w3v[oft] = W3[oft*16 + r16];
    }

    for (int t = blockIdx.x; t < ntiles; t += (int)gridDim.x){
        const int rowbase = t*TROWS + wv*16;
        const int myrow   = rowbase + r16;
        const bool vload  = myrow < n;
        const float* xrow = node1 + (size_t)myrow * DD;

        // ---- load + split x -> B1 frags (HBM -> regs, no LDS) ----
        bf16x8 B1h[4], B1l[4];
        #pragma unroll
        for (int ks = 0; ks < 4; ++ks){
            f32x4 a = {0.f,0.f,0.f,0.f}, b = {0.f,0.f,0.f,0.f};
            if (vload){
                a = *(const f32x4*)(xrow + ks*32 + hg4*8);
                b = *(const f32x4*)(xrow + ks*32 + hg4*8 + 4);
            }
            union { ushort4 q[2]; bf16x8 v; } H, L;
            split2(a[0], H.q[0].x, L.q[0].x);
            split2(a[1], H.q[0].y, L.q[0].y);
            split2(a[2], H.q[0].z, L.q[0].z);
            split2(a[3], H.q[0].w, L.q[0].w);
            split2(b[0], H.q[1].x, L.q[1].x);
            split2(b[1], H.q[1].y, L.q[1].y);
            split2(b[2], H.q[1].z, L.q[1].z);
            split2(b[3], H.q[1].w, L.q[1].w);
            B1h[ks] = H.v; B1l[ks] = L.v;
        }

        // ---- layer 1: A = permuted W1 (LDS), B = x. acc1[ft][j] = h1[pi(ft,hg4,j)][r16] ----
        f32x4 acc1[8];
        #pragma unroll
        for (int ft = 0; ft < 8; ++ft){
            const float4 bv = *(const float4*)&g_b1p[32*(ft>>1) + 8*hg4 + 4*(ft&1)];
            acc1[ft][0] = bv.x; acc1[ft][1] = bv.y; acc1[ft][2] = bv.z; acc1[ft][3] = bv.w;
        }
        #pragma unroll
        for (int ks = 0; ks < 4; ++ks){
            #pragma unroll
            for (int ft = 0; ft < 8; ++ft){
                const bf16x8 Ah = WL[((0*4 + ks)*8 + ft)*64 + lane];
                const bf16x8 Al = WL[((1*4 + ks)*8 + ft)*64 + lane];
                acc1[ft] = __builtin_amdgcn_mfma_f32_16x16x32_bf16(Ah, B1h[ks], acc1[ft], 0,0,0);
                acc1[ft] = __builtin_amdgcn_mfma_f32_16x16x32_bf16(Ah, B1l[ks], acc1[ft], 0,0,0);
                acc1[ft] = __builtin_amdgcn_mfma_f32_16x16x32_bf16(Al, B1h[ks], acc1[ft], 0,0,0);
            }
        }

        // ---- lane-local transition: pi was chosen so acc1 IS layer-2's A-frag ----
        // A2 slot (ks, hg4, r) needs h1[row r16][true feat 32ks+8hg4+r]
        //  = relu(acc1[2ks + (r>>2)][r&3])  -- pure repack, no cross-lane movement
        bf16x8 A2h[4], A2l[4];
        #pragma unroll
        for (int ks = 0; ks < 4; ++ks){
            union { ushort4 q[2]; bf16x8 v; } H, L;
            #pragma unroll
            for (int half = 0; half < 2; ++half){
                #pragma unroll
                for (int j = 0; j < 4; ++j){
                    float v = fmaxf(acc1[2*ks + half][j], 0.f);
                    unsigned short h_, l_;
                    split2(v, h_, l_);
                    ((unsigned short*)&H.q[half])[j] = h_;
                    ((unsigned short*)&L.q[half])[j] = l_;
                }
            }
            A2h[ks] = H.v; A2l[ks] = L.v;
        }

        // ---- layer 2: A = h1 (regs), B = W2 (LDS). acc2[oft][j] = h2[row 4hg4+j][oft*16+r16] ----
        f32x4 acc2[8];
        #pragma unroll
        for (int oft = 0; oft < 8; ++oft){
            const float bb = b2v[oft];
            acc2[oft][0] = bb; acc2[oft][1] = bb; acc2[oft][2] = bb; acc2[oft][3] = bb;
        }
        #pragma unroll
        for (int ks = 0; ks < 4; ++ks){
            #pragma unroll
            for (int oft = 0; oft < 8; ++oft){
                const bf16x8 Bh = WL[((2*4 + ks)*8 + oft)*64 + lane];
                const bf16x8 Bl = WL[((3*4 + ks)*8 + oft)*64 + lane];
                acc2[oft] = __builtin_amdgcn_mfma_f32_16x16x32_bf16(A2h[ks], Bh, acc2[oft], 0,0,0);
                acc2[oft] = __builtin_amdgcn_mfma_f32_16x16x32_bf16(A2h[ks], Bl, acc2[oft], 0,0,0);
                acc2[oft] = __builtin_amdgcn_mfma_f32_16x16x32_bf16(A2l[ks], Bh, acc2[oft], 0,0,0);
            }
        }

        // ---- layer 3: s[row 4hg4+j] = sum over features (oft x r16) ----
        float p[4] = {0.f, 0.f, 0.f, 0.f};
        #pragma unroll
        for (int oft = 0; oft < 8; ++oft){
            const float w3 = w3v[oft];
            p[0] = fmaf(fmaxf(acc2[oft][0], 0.f), w3, p[0]);
            p[1] = fmaf(fmaxf(acc2[oft][1], 0.f), w3, p[1]);
            p[2] = fmaf(fmaxf(acc2[oft][2], 0.f), w3, p[2]);
            p[3] = fmaf(fmaxf(acc2[oft][3], 0.f), w3, p[3]);
        }
        #pragma unroll
        for (int j = 0; j < 4; ++j){
            p[j] += __shfl_xor(p[j], 1);
            p[j] += __shfl_xor(p[j], 2);
            p[j] += __shfl_xor(p[j], 4);
            p[j] += __shfl_xor(p[j], 8);
        }

        // write scores (lanes r16==0 own rows rowbase + 4hg4 + j)
        if (r16 == 0){
            #pragma unroll
            for (int j = 0; j < 4; ++j){
                const int rr = rowbase + 4*hg4 + j;
                if (rr < n) out[rr] = p[j];
            }
        }

        // per-wave softmax stats over its 16 rows
        float m = -3.0e38f;
        #pragma unroll
        for (int j = 0; j < 4; ++j){
            const int rr = rowbase + 4*hg4 + j;
            if (rr < n) m = fmaxf(m, p[j]);
        }
        m = fmaxf(m, __shfl_xor(m, 16));
        m = fmaxf(m, __shfl_xor(m, 32));
        float e = 0.f;
        if (r16 == 0){
            #pragma unroll
            for (int j = 0; j < 4; ++j){
                const int rr = rowbase + 4*hg4 + j;
                if (rr < n) e += expf(p[j] - m);
            }
        }
        e += __shfl_xor(e, 16);
        e += __shfl_xor(e, 32);
        if (lane == 0){ g_pm[t*NWAVE + wv] = m; g_ps[t*NWAVE + wv] = e; }
    }
}

__global__ __launch_bounds__(1024)
void k_combine(int ng)
{
    __shared__ float red[17];
    const int tid = threadIdx.x, lane = tid & 63, wv = tid >> 6;

    float m = -3.0e38f;
    for (int i = tid; i < ng; i += 1024) m = fmaxf(m, g_pm[i]);
    #pragma unroll
    for (int off = 32; off > 0; off >>= 1) m = fmaxf(m, __shfl_xor(m, off));
    if (lane == 0) red[wv] = m;
    __syncthreads();
    if (tid < 64){
        float v = (lane < 16) ? red[lane] : -3.0e38f;
        #pragma unroll
        for (int off = 32; off > 0; off >>= 1) v = fmaxf(v, __shfl_xor(v, off));
        if (lane == 0) red[16] = v;
    }
    __syncthreads();
    m = red[16];

    float z = 0.f;
    for (int i = tid; i < ng; i += 1024) z += g_ps[i] * expf(g_pm[i] - m);
    #pragma unroll
    for (int off = 32; off > 0; off >>= 1) z += __shfl_xor(z, off);
    __syncthreads();
    if (lane == 0) red[wv] = z;
    __syncthreads();
    if (tid < 64){
        float v = (lane < 16) ? red[lane] : 0.f;
        #pragma unroll
        for (int off = 32; off > 0; off >>= 1) v += __shfl_xor(v, off);
        if (lane == 0){ g_m = m; g_invZ = 1.0f / v; }
    }
}

__global__ __launch_bounds__(256)
void k_norm(float* __restrict__ s, int n)
{
    const int i = blockIdx.x * 256 + threadIdx.x;
    const float m = g_m, r = g_invZ;
    const int n4 = n >> 2;
    if (i < n4){
        float4 v = reinterpret_cast<float4*>(s)[i];
        v.x = expf(v.x - m) * r;
        v.y = expf(v.y - m) * r;
        v.z = expf(v.z - m) * r;
        v.w = expf(v.w - m) * r;
        reinterpret_cast<float4*>(s)[i] = v;
    }
    const int rem = n - (n4 << 2);
    if (i < rem){
        int t = (n4 << 2) + i;
        s[t] = expf(s[t] - m) * r;
    }
}

extern "C" void kernel_launch(void* const* d_in, const int* in_sizes, int n_in,
                              void* d_out, int out_size, void* d_ws, size_t ws_size,
                              hipStream_t stream)
{
    const float* node1 = (const float*)d_in[0];
    const float* urep  = (const float*)d_in[1];
    const float* W1    = (const float*)d_in[3];
    const float* b1    = (const float*)d_in[4];
    const float* W2    = (const float*)d_in[5];
    const float* b2    = (const float*)d_in[6];
    const float* W3    = (const float*)d_in[7];
    float* out = (float*)d_out;

    const int n      = in_sizes[0] / DD;              // 200000
    const int ntiles = (n + TROWS - 1) / TROWS;       // 782
    const int ng     = ntiles * NWAVE;                // 12512

    // allow 128 KB dynamic LDS (idempotent, not a stream op)
    hipFuncSetAttribute((const void*)k_mlp,
                        hipFuncAttributeMaxDynamicSharedMemorySize, 131072);

    k_prep<<<dim3(33), dim3(256), 0, stream>>>(W1, W2, b1, urep);
    k_mlp<<<dim3(GRID_MLP), dim3(TPB), 131072, stream>>>(node1, b2, W3, out, n);
    k_combine<<<dim3(1), dim3(1024), 0, stream>>>(ng);

    const int n4  = n >> 2;
    const int nb3 = (n4 + 255) / 256 > 0 ? (n4 + 255) / 256 : 1;
    k_norm<<<dim3(nb3), dim3(256), 0, stream>>>(out, n);
}